// Round 7
// baseline (827.528 us; speedup 1.0000x reference)
//
#include <hip/hip_runtime.h>
#include <cmath>

#define N_NODES 50000
#define N_EDGES 800000
#define N_FEAT 128
#define DIM 64
#define N_GRAPHS 512
#define GGRID ((N_NODES + 63) / 64)         // 782 gemm1 / bucket tiles
#define NBKT GGRID                          // bucket = dst>>6, 782 buckets
#define BH_BLK 128                          // bucket-sort blocks
#define EPB (N_EDGES / BH_BLK)              // 6250 edges per sort block
#define NCNT (NBKT * BH_BLK)                // 100096 count-matrix entries
#define P2_NBLK ((NCNT + 511) / 512)        // 196 scan blocks

// bf16 storage helpers (RNE). Storage-only: all math in fp32.
__device__ __forceinline__ unsigned short f2bf(float f) {
  union { float f; unsigned int u; } v; v.f = f;
  return (unsigned short)((v.u + 0x7FFFu + ((v.u >> 16) & 1u)) >> 16);
}
__device__ __forceinline__ float bf2f(unsigned short u) {
  union { unsigned int u; float f; } v; v.u = (unsigned int)u << 16;
  return v.f;
}

// ---------------------------------------------------------------------------
// GEMM body for gemm1: out[M][64] = A[M][128] @ W[128][64], bf16 output rows.
template<int K>
__device__ __forceinline__ void gemm_body_bf(const float* __restrict__ A,
                                             const float* __restrict__ W,
                                             unsigned short* __restrict__ out,
                                             int M, int row0, int tid,
                                             float* sX, float* sW) {
  const int tx = tid & 15, ty = tid >> 4;
  const int q = tid & 7, r0 = tid >> 3;
  float acc[4][4] = {};

  for (int kb = 0; kb < K; kb += 32) {
    __syncthreads();
    if ((kb & 63) == 0) {
#pragma unroll
      for (int i = 0; i < 16; i++)
        sW[i * 256 + tid] = W[kb * 64 + i * 256 + tid];
    }
#pragma unroll
    for (int rr = 0; rr < 64; rr += 32) {
      int r = r0 + rr;
      int gr = row0 + r;
      float4 v = make_float4(0.f, 0.f, 0.f, 0.f);
      if (gr < M) v = *(const float4*)&A[(size_t)gr * K + kb + q * 4];
      *(float4*)&sX[r * 36 + q * 4] = v;
    }
    __syncthreads();

    const int kw = kb & 63;
#pragma unroll 4
    for (int k = 0; k < 32; k += 4) {
      float4 wv[4];
#pragma unroll
      for (int kk = 0; kk < 4; kk++)
        wv[kk] = *(const float4*)&sW[(kw + k + kk) * 64 + tx * 4];
#pragma unroll
      for (int r = 0; r < 4; r++) {
        float4 xv = *(const float4*)&sX[(ty * 4 + r) * 36 + k];
        const float xs[4] = {xv.x, xv.y, xv.z, xv.w};
#pragma unroll
        for (int kk = 0; kk < 4; kk++) {
          acc[r][0] += xs[kk] * wv[kk].x;
          acc[r][1] += xs[kk] * wv[kk].y;
          acc[r][2] += xs[kk] * wv[kk].z;
          acc[r][3] += xs[kk] * wv[kk].w;
        }
      }
    }
  }

#pragma unroll
  for (int r = 0; r < 4; r++) {
    int gr = row0 + ty * 4 + r;
    if (gr < M) {
      ushort4 u;
      u.x = f2bf(acc[r][0]); u.y = f2bf(acc[r][1]);
      u.z = f2bf(acc[r][2]); u.w = f2bf(acc[r][3]);
      *(ushort4*)&out[(size_t)gr * 64 + tx * 4] = u;
    }
  }
}

// fused dispatch 1: blocks [0,GGRID) = gemm1 (x@W1 -> h1 bf16);
// blocks [GGRID, GGRID+BH_BLK) = per-block bucket histogram of dst>>6.
// cnt layout bucket-major: cnt[b*BH_BLK + k].
__global__ __launch_bounds__(256) void gemm1_bhist(const float* __restrict__ x,
                                                   const float* __restrict__ W1,
                                                   unsigned short* __restrict__ h1,
                                                   const int* __restrict__ dst,
                                                   int* __restrict__ cnt) {
  __shared__ float sX[64 * 36];
  __shared__ float sW[64 * 64];
  const int tid = threadIdx.x;
  if (blockIdx.x < GGRID) {
    gemm_body_bf<N_FEAT>(x, W1, h1, N_NODES, blockIdx.x * 64, tid, sX, sW);
  } else {
    int* lh = (int*)sX;                       // reuse LDS: 782 ints
    const int k = blockIdx.x - GGRID;
    for (int i = tid; i < NBKT; i += 256) lh[i] = 0;
    __syncthreads();
    const int base = k * EPB;
    for (int j = tid; j < EPB; j += 256)
      atomicAdd(&lh[dst[base + j] >> 6], 1);
    __syncthreads();
    for (int i = tid; i < NBKT; i += 256) cnt[i * BH_BLK + k] = lh[i];
  }
}

// ---------------------------------------------------------------------------
// hierarchical exclusive scan over cnt[NCNT] (in-place) + bucket_ptr extract
__global__ __launch_bounds__(512) void psum512(const int* __restrict__ cnt,
                                               int* __restrict__ partials) {
  __shared__ int ws[8];
  int gid = blockIdx.x * 512 + threadIdx.x;
  int v = (gid < NCNT) ? cnt[gid] : 0;
#pragma unroll
  for (int off = 32; off; off >>= 1) v += __shfl_down(v, off, 64);
  int lane = threadIdx.x & 63, w = threadIdx.x >> 6;
  if (lane == 0) ws[w] = v;
  __syncthreads();
  if (threadIdx.x == 0) {
    int s = 0;
#pragma unroll
    for (int i = 0; i < 8; i++) s += ws[i];
    partials[blockIdx.x] = s;
  }
}

__global__ __launch_bounds__(256) void scan_partials(int* __restrict__ partials) {
  __shared__ int buf[256];
  int tid = threadIdx.x;
  int v = (tid < P2_NBLK) ? partials[tid] : 0;
  buf[tid] = v;
  __syncthreads();
  for (int off = 1; off < 256; off <<= 1) {
    int t = (tid >= off) ? buf[tid - off] : 0;
    __syncthreads();
    buf[tid] += t;
    __syncthreads();
  }
  if (tid < P2_NBLK) partials[tid] = buf[tid] - v;   // exclusive
}

__global__ __launch_bounds__(512) void sblocks512(int* __restrict__ cnt,
                                                  const int* __restrict__ partials,
                                                  int* __restrict__ bucket_ptr) {
  __shared__ int buf[512];
  int tid = threadIdx.x;
  int gid = blockIdx.x * 512 + tid;
  int v = (gid < NCNT) ? cnt[gid] : 0;
  buf[tid] = v;
  __syncthreads();
  for (int off = 1; off < 512; off <<= 1) {
    int t = (tid >= off) ? buf[tid - off] : 0;
    __syncthreads();
    buf[tid] += t;
    __syncthreads();
  }
  int excl = buf[tid] - v + partials[blockIdx.x];
  if (gid < NCNT) {
    cnt[gid] = excl;                                  // in-place offsets
    if ((gid & (BH_BLK - 1)) == 0) bucket_ptr[gid / BH_BLK] = excl;
    if (gid == NCNT - 1) bucket_ptr[NBKT] = excl + v; // == N_EDGES
  }
}

// ---------------------------------------------------------------------------
// scatter edges into bucket-sorted order, packed (src<<6)|dst_local.
// Per-block per-bucket runs are contiguous (~8 edges = 32B) -> L2 merges.
__global__ __launch_bounds__(256) void bscatter(const int* __restrict__ src,
                                                const int* __restrict__ dst,
                                                const int* __restrict__ cnt,
                                                unsigned int* __restrict__ ebuf) {
  __shared__ int loff[NBKT];
  const int tid = threadIdx.x, k = blockIdx.x;
  for (int i = tid; i < NBKT; i += 256) loff[i] = cnt[i * BH_BLK + k];
  __syncthreads();
  const int base = k * EPB;
  for (int j = tid; j < EPB; j += 256) {
    int e = base + j;
    int d = dst[e];
    int pos = atomicAdd(&loff[d >> 6], 1);
    ebuf[pos] = ((unsigned int)src[e] << 6) | (unsigned int)(d & 63);
  }
}

// ---------------------------------------------------------------------------
// accumulate a bucket's edges into the 64x68 fp32 LDS tile via ds_add_f32.
// lane = (eo 0..3 edge slot, qfo feature-quad*4); 2x unroll = 8 rows in flight.
__device__ __forceinline__ void accum_bucket(const unsigned short* __restrict__ h,
                                             const unsigned int* __restrict__ ebuf,
                                             int p0, int p1, int w, int eo, int qfo,
                                             float* __restrict__ sA) {
  for (int i = p0 + w * 4 + eo; i < p1; i += 32) {
    int ib = i + 16;
    unsigned int ua = ebuf[i];
    bool hb = ib < p1;
    unsigned int ub = hb ? ebuf[ib] : ua;
    ushort4 ra = *(const ushort4*)&h[(size_t)(ua >> 6) * 64 + qfo];
    ushort4 rb = *(const ushort4*)&h[(size_t)(ub >> 6) * 64 + qfo];
    float* pa = &sA[(ua & 63) * 68 + qfo];
    atomicAdd(pa + 0, bf2f(ra.x));
    atomicAdd(pa + 1, bf2f(ra.y));
    atomicAdd(pa + 2, bf2f(ra.z));
    atomicAdd(pa + 3, bf2f(ra.w));
    if (hb) {
      float* pb = &sA[(ub & 63) * 68 + qfo];
      atomicAdd(pb + 0, bf2f(rb.x));
      atomicAdd(pb + 1, bf2f(rb.y));
      atomicAdd(pb + 2, bf2f(rb.z));
      atomicAdd(pb + 3, bf2f(rb.w));
    }
  }
}

// ---------------------------------------------------------------------------
// fused layer-1 aggregate + relu + gemm2: block = bucket = 64-node tile.
__global__ __launch_bounds__(256) void gather_gemm2(
    const unsigned short* __restrict__ h1, const unsigned int* __restrict__ ebuf,
    const int* __restrict__ bucket_ptr, const float* __restrict__ W2,
    unsigned short* __restrict__ h2) {
  __shared__ float sA[64 * 68];
  __shared__ float sW[64 * 64];
  const int tid = threadIdx.x;
  const int b = blockIdx.x, row0 = b * 64;
  const int lane = tid & 63, w = tid >> 6;
  const int eo = lane >> 4, qfo = (lane & 15) << 2;

  for (int i = tid; i < 64 * 68; i += 256) sA[i] = 0.f;
#pragma unroll
  for (int i = 0; i < 16; i++) sW[i * 256 + tid] = W2[i * 256 + tid];
  __syncthreads();

  accum_bucket(h1, ebuf, bucket_ptr[b], bucket_ptr[b + 1], w, eo, qfo, sA);
  __syncthreads();
  // relu (layer-1 activation) in place
  for (int i = tid; i < 64 * 68; i += 256) sA[i] = fmaxf(sA[i], 0.f);
  __syncthreads();

  const int tx = tid & 15, ty = tid >> 4;
  float acc[4][4] = {};
#pragma unroll 4
  for (int k = 0; k < 64; k += 4) {
    float4 wv[4];
#pragma unroll
    for (int kk = 0; kk < 4; kk++)
      wv[kk] = *(const float4*)&sW[(k + kk) * 64 + tx * 4];
#pragma unroll
    for (int r = 0; r < 4; r++) {
      float4 xv = *(const float4*)&sA[(ty * 4 + r) * 68 + k];
      const float xs[4] = {xv.x, xv.y, xv.z, xv.w};
#pragma unroll
      for (int kk = 0; kk < 4; kk++) {
        acc[r][0] += xs[kk] * wv[kk].x;
        acc[r][1] += xs[kk] * wv[kk].y;
        acc[r][2] += xs[kk] * wv[kk].z;
        acc[r][3] += xs[kk] * wv[kk].w;
      }
    }
  }
#pragma unroll
  for (int r = 0; r < 4; r++) {
    int gr = row0 + ty * 4 + r;
    if (gr < N_NODES) {
      ushort4 u;
      u.x = f2bf(acc[r][0]); u.y = f2bf(acc[r][1]);
      u.z = f2bf(acc[r][2]); u.w = f2bf(acc[r][3]);
      *(ushort4*)&h2[(size_t)gr * 64 + tx * 4] = u;
    }
  }
}

// ---------------------------------------------------------------------------
// layer-2 aggregate: bucket tile accumulate, write agg fp32 coalesced.
__global__ __launch_bounds__(256) void gather_agg(
    const unsigned short* __restrict__ h2, const unsigned int* __restrict__ ebuf,
    const int* __restrict__ bucket_ptr, float* __restrict__ agg) {
  __shared__ float sA[64 * 68];
  const int tid = threadIdx.x;
  const int b = blockIdx.x, row0 = b * 64;
  const int lane = tid & 63, w = tid >> 6;
  const int eo = lane >> 4, qfo = (lane & 15) << 2;

  for (int i = tid; i < 64 * 68; i += 256) sA[i] = 0.f;
  __syncthreads();
  accum_bucket(h2, ebuf, bucket_ptr[b], bucket_ptr[b + 1], w, eo, qfo, sA);
  __syncthreads();

  const int c4 = (tid & 15) * 4, r0 = tid >> 4;
#pragma unroll
  for (int rr = 0; rr < 64; rr += 16) {
    int r = r0 + rr;
    int gr = row0 + r;
    if (gr < N_NODES)
      *(float4*)&agg[(size_t)gr * 64 + c4] = *(float4*)&sA[r * 68 + c4];
  }
}

// ---------------------------------------------------------------------------
// batch is SORTED -> contiguous segment per graph. 4 waves split the rows.
__global__ __launch_bounds__(256) void pool_fc(const float* __restrict__ agg,
                                               const int* __restrict__ batch,
                                               const float* __restrict__ Wfc,
                                               float* __restrict__ out) {
  __shared__ float sacc[4][64];
  int g = blockIdx.x;
  int tid = threadIdx.x, lane = tid & 63, w = tid >> 6;

  int lo = 0, hi = N_NODES;
  while (lo < hi) { int mid = (lo + hi) >> 1; if (batch[mid] < g) lo = mid + 1; else hi = mid; }
  const int start = lo;
  hi = N_NODES;
  while (lo < hi) { int mid = (lo + hi) >> 1; if (batch[mid] < g + 1) lo = mid + 1; else hi = mid; }
  const int end = lo;

  float acc = 0.f;
  for (int n = start + w; n < end; n += 4) acc += agg[(size_t)n * 64 + lane];
  sacc[w][lane] = acc;
  __syncthreads();
  if (w == 0) {
    float v = sacc[0][lane] + sacc[1][lane] + sacc[2][lane] + sacc[3][lane];
    v /= fmaxf((float)(end - start), 1.f);
    v *= Wfc[lane];
#pragma unroll
    for (int off = 32; off; off >>= 1) v += __shfl_down(v, off, 64);
    if (lane == 0) out[g] = 1.f / (1.f + expf(-v));
  }
}

// ---------------------------------------------------------------------------
extern "C" void kernel_launch(void* const* d_in, const int* in_sizes, int n_in,
                              void* d_out, int out_size, void* d_ws, size_t ws_size,
                              hipStream_t stream) {
  const float* x     = (const float*)d_in[0];
  const int*   ei    = (const int*)d_in[1];   // [2, E]: src then dst
  const int*   batch = (const int*)d_in[2];
  const float* W1    = (const float*)d_in[3];
  const float* W2    = (const float*)d_in[4];
  const float* Wfc   = (const float*)d_in[5];
  float*       out   = (float*)d_out;

  const int* src = ei;
  const int* dst = ei + N_EDGES;

  // workspace layout (~29.3 MB)
  char* ws = (char*)d_ws;
  unsigned short* h1 = (unsigned short*)(ws);                  // [N,64] bf16
  unsigned short* h2 = h1 + (size_t)N_NODES * DIM;             // [N,64] bf16
  float* agg = (float*)(ws + (size_t)N_NODES * DIM * 4);       // [N,64] fp32
  int*   cnt = (int*)(ws + (size_t)N_NODES * DIM * 8);         // [NCNT]
  unsigned int* ebuf = (unsigned int*)(cnt + NCNT);            // [E] packed
  int*   bucket_ptr  = (int*)(ebuf + N_EDGES);                 // [NBKT+1]
  int*   partials    = bucket_ptr + NBKT + 1;                  // [P2_NBLK]

  // dispatch 1: gemm1 (h1 = bf16(x@W1)) || bucket histogram
  gemm1_bhist<<<GGRID + BH_BLK, 256, 0, stream>>>(x, W1, h1, dst, cnt);

  // exclusive scan of count matrix -> per-(bucket,block) offsets + bucket_ptr
  psum512<<<P2_NBLK, 512, 0, stream>>>(cnt, partials);
  scan_partials<<<1, 256, 0, stream>>>(partials);
  sblocks512<<<P2_NBLK, 512, 0, stream>>>(cnt, partials, bucket_ptr);

  // bucket-sorted edge buffer (packed src|dst_local)
  bscatter<<<BH_BLK, 256, 0, stream>>>(src, dst, cnt, ebuf);

  // layer 1 aggregate + relu + gemm2 (fused, bucket-parallel)
  gather_gemm2<<<NBKT, 256, 0, stream>>>(h1, ebuf, bucket_ptr, W2, h2);

  // layer 2 aggregate (bucket-parallel), then mean-pool + FC + sigmoid
  gather_agg<<<NBKT, 256, 0, stream>>>(h2, ebuf, bucket_ptr, agg);
  pool_fc<<<N_GRAPHS, 256, 0, stream>>>(agg, batch, Wfc, out);
}

// Round 8
// 219.085 us; speedup vs baseline: 3.7772x; 3.7772x over previous
//
#include <hip/hip_runtime.h>
#include <cmath>

#define N_NODES 50000
#define N_EDGES 800000
#define N_FEAT 128
#define DIM 64
#define N_GRAPHS 512
#define GGRID ((N_NODES + 63) / 64)         // 782 gemm1 tiles / buckets
#define NBKT GGRID                          // bucket = dst>>6
#define BH_BLK 128                          // bucket-sort blocks
#define EPB (N_EDGES / BH_BLK)              // 6250 edges per sort block
#define NCNT (NBKT * BH_BLK)                // 100096 count-matrix entries
#define P2_NBLK ((NCNT + 511) / 512)        // 196 scan blocks

// bf16 storage helpers (RNE). Storage-only: all math in fp32.
__device__ __forceinline__ unsigned short f2bf(float f) {
  union { float f; unsigned int u; } v; v.f = f;
  return (unsigned short)((v.u + 0x7FFFu + ((v.u >> 16) & 1u)) >> 16);
}
__device__ __forceinline__ float bf2f(unsigned short u) {
  union { unsigned int u; float f; } v; v.u = (unsigned int)u << 16;
  return v.f;
}

// ---------------------------------------------------------------------------
// GEMM body for gemm1: out[M][64] = A[M][128] @ W[128][64], bf16 output rows.
template<int K>
__device__ __forceinline__ void gemm_body_bf(const float* __restrict__ A,
                                             const float* __restrict__ W,
                                             unsigned short* __restrict__ out,
                                             int M, int row0, int tid,
                                             float* sX, float* sW) {
  const int tx = tid & 15, ty = tid >> 4;
  const int q = tid & 7, r0 = tid >> 3;
  float acc[4][4] = {};

  for (int kb = 0; kb < K; kb += 32) {
    __syncthreads();
    if ((kb & 63) == 0) {
#pragma unroll
      for (int i = 0; i < 16; i++)
        sW[i * 256 + tid] = W[kb * 64 + i * 256 + tid];
    }
#pragma unroll
    for (int rr = 0; rr < 64; rr += 32) {
      int r = r0 + rr;
      int gr = row0 + r;
      float4 v = make_float4(0.f, 0.f, 0.f, 0.f);
      if (gr < M) v = *(const float4*)&A[(size_t)gr * K + kb + q * 4];
      *(float4*)&sX[r * 36 + q * 4] = v;
    }
    __syncthreads();

    const int kw = kb & 63;
#pragma unroll 4
    for (int k = 0; k < 32; k += 4) {
      float4 wv[4];
#pragma unroll
      for (int kk = 0; kk < 4; kk++)
        wv[kk] = *(const float4*)&sW[(kw + k + kk) * 64 + tx * 4];
#pragma unroll
      for (int r = 0; r < 4; r++) {
        float4 xv = *(const float4*)&sX[(ty * 4 + r) * 36 + k];
        const float xs[4] = {xv.x, xv.y, xv.z, xv.w};
#pragma unroll
        for (int kk = 0; kk < 4; kk++) {
          acc[r][0] += xs[kk] * wv[kk].x;
          acc[r][1] += xs[kk] * wv[kk].y;
          acc[r][2] += xs[kk] * wv[kk].z;
          acc[r][3] += xs[kk] * wv[kk].w;
        }
      }
    }
  }

#pragma unroll
  for (int r = 0; r < 4; r++) {
    int gr = row0 + ty * 4 + r;
    if (gr < M) {
      ushort4 u;
      u.x = f2bf(acc[r][0]); u.y = f2bf(acc[r][1]);
      u.z = f2bf(acc[r][2]); u.w = f2bf(acc[r][3]);
      *(ushort4*)&out[(size_t)gr * 64 + tx * 4] = u;
    }
  }
}

// fused dispatch 1: blocks [0,GGRID) = gemm1 (x@W1 -> h1 bf16);
// blocks [GGRID, GGRID+BH_BLK) = per-block bucket histogram of dst>>6.
// cnt layout bucket-major: cnt[b*BH_BLK + k].
__global__ __launch_bounds__(256) void gemm1_bhist(const float* __restrict__ x,
                                                   const float* __restrict__ W1,
                                                   unsigned short* __restrict__ h1,
                                                   const int* __restrict__ dst,
                                                   int* __restrict__ cnt) {
  __shared__ float sX[64 * 36];
  __shared__ float sW[64 * 64];
  const int tid = threadIdx.x;
  if (blockIdx.x < GGRID) {
    gemm_body_bf<N_FEAT>(x, W1, h1, N_NODES, blockIdx.x * 64, tid, sX, sW);
  } else {
    int* lh = (int*)sX;                       // reuse LDS: 782 ints
    const int k = blockIdx.x - GGRID;
    for (int i = tid; i < NBKT; i += 256) lh[i] = 0;
    __syncthreads();
    const int base = k * EPB;
    for (int j = tid; j < EPB; j += 256)
      atomicAdd(&lh[dst[base + j] >> 6], 1);
    __syncthreads();
    for (int i = tid; i < NBKT; i += 256) cnt[i * BH_BLK + k] = lh[i];
  }
}

// ---------------------------------------------------------------------------
// hierarchical exclusive scan over cnt[NCNT] (in-place) + bucket_ptr extract
__global__ __launch_bounds__(512) void psum512(const int* __restrict__ cnt,
                                               int* __restrict__ partials) {
  __shared__ int ws[8];
  int gid = blockIdx.x * 512 + threadIdx.x;
  int v = (gid < NCNT) ? cnt[gid] : 0;
#pragma unroll
  for (int off = 32; off; off >>= 1) v += __shfl_down(v, off, 64);
  int lane = threadIdx.x & 63, w = threadIdx.x >> 6;
  if (lane == 0) ws[w] = v;
  __syncthreads();
  if (threadIdx.x == 0) {
    int s = 0;
#pragma unroll
    for (int i = 0; i < 8; i++) s += ws[i];
    partials[blockIdx.x] = s;
  }
}

__global__ __launch_bounds__(256) void scan_partials(int* __restrict__ partials) {
  __shared__ int buf[256];
  int tid = threadIdx.x;
  int v = (tid < P2_NBLK) ? partials[tid] : 0;
  buf[tid] = v;
  __syncthreads();
  for (int off = 1; off < 256; off <<= 1) {
    int t = (tid >= off) ? buf[tid - off] : 0;
    __syncthreads();
    buf[tid] += t;
    __syncthreads();
  }
  if (tid < P2_NBLK) partials[tid] = buf[tid] - v;   // exclusive
}

__global__ __launch_bounds__(512) void sblocks512(int* __restrict__ cnt,
                                                  const int* __restrict__ partials,
                                                  int* __restrict__ bucket_ptr) {
  __shared__ int buf[512];
  int tid = threadIdx.x;
  int gid = blockIdx.x * 512 + tid;
  int v = (gid < NCNT) ? cnt[gid] : 0;
  buf[tid] = v;
  __syncthreads();
  for (int off = 1; off < 512; off <<= 1) {
    int t = (tid >= off) ? buf[tid - off] : 0;
    __syncthreads();
    buf[tid] += t;
    __syncthreads();
  }
  int excl = buf[tid] - v + partials[blockIdx.x];
  if (gid < NCNT) {
    cnt[gid] = excl;                                  // in-place offsets
    if ((gid & (BH_BLK - 1)) == 0) bucket_ptr[gid / BH_BLK] = excl;
    if (gid == NCNT - 1) bucket_ptr[NBKT] = excl + v; // == N_EDGES
  }
}

// ---------------------------------------------------------------------------
// scatter edges into bucket-sorted order, packed (src<<6)|dst_local.
// Per-block per-bucket runs are contiguous (~8 edges = 32B) -> L2 merges.
__global__ __launch_bounds__(256) void bscatter(const int* __restrict__ src,
                                                const int* __restrict__ dst,
                                                const int* __restrict__ cnt,
                                                unsigned int* __restrict__ ebuf) {
  __shared__ int loff[NBKT];
  const int tid = threadIdx.x, k = blockIdx.x;
  for (int i = tid; i < NBKT; i += 256) loff[i] = cnt[i * BH_BLK + k];
  __syncthreads();
  const int base = k * EPB;
  for (int j = tid; j < EPB; j += 256) {
    int e = base + j;
    int d = dst[e];
    int pos = atomicAdd(&loff[d >> 6], 1);
    ebuf[pos] = ((unsigned int)src[e] << 6) | (unsigned int)(d & 63);
  }
}

// ---------------------------------------------------------------------------
// per bucket: 64-entry dst_local histogram -> row_ptr, then redistribute
// ebuf[p0..p1) into exact per-node CSR order in col[p0..p1) (contiguous 4KB
// writes per block -> no write amplification).
__global__ __launch_bounds__(256) void bucket_to_csr(
    const unsigned int* __restrict__ ebuf, const int* __restrict__ bucket_ptr,
    int* __restrict__ row_ptr, int* __restrict__ col) {
  __shared__ int lh[64];
  __shared__ int loff[64];
  const int b = blockIdx.x, tid = threadIdx.x;
  const int p0 = bucket_ptr[b], p1 = bucket_ptr[b + 1];

  if (tid < 64) lh[tid] = 0;
  __syncthreads();
  for (int i = p0 + tid; i < p1; i += 256)
    atomicAdd(&lh[ebuf[i] & 63], 1);
  __syncthreads();

  if (tid < 64) {                       // wave-0 exclusive scan of 64 degrees
    int v = lh[tid];
    int s = v;
#pragma unroll
    for (int off = 1; off < 64; off <<= 1) {
      int t = __shfl_up(s, off, 64);
      if (tid >= off) s += t;
    }
    int excl = s - v;
    loff[tid] = excl;
    int gid = b * 64 + tid;
    if (gid <= N_NODES) row_ptr[gid] = p0 + excl;   // last bucket: zero-degree
  }                                                  // tail gives row_ptr[N]=E
  __syncthreads();

  for (int i = p0 + tid; i < p1; i += 256) {
    unsigned int u = ebuf[i];
    int pos = atomicAdd(&loff[u & 63], 1);
    col[p0 + pos] = (int)(u >> 6);
  }
}

// ---------------------------------------------------------------------------
// per-node gather partial over bf16 rows: lane = (eo 0..3, qfo quad*4).
// 16 lanes x ushort4 (8B) = one 128B coalesced row per edge.
__device__ __forceinline__ float4 gather_node_bf(const unsigned short* __restrict__ h,
                                                 const int* __restrict__ col,
                                                 int i, int end, int eo, int qfo,
                                                 float4 acc) {
  for (; i + 8 <= end; i += 8) {
    int s0 = col[i + eo];
    int s1 = col[i + 4 + eo];
    ushort4 u0 = *(const ushort4*)&h[(size_t)s0 * 64 + qfo];
    ushort4 u1 = *(const ushort4*)&h[(size_t)s1 * 64 + qfo];
    acc.x += bf2f(u0.x) + bf2f(u1.x);
    acc.y += bf2f(u0.y) + bf2f(u1.y);
    acc.z += bf2f(u0.z) + bf2f(u1.z);
    acc.w += bf2f(u0.w) + bf2f(u1.w);
  }
  for (; i + 4 <= end; i += 4) {
    int s = col[i + eo];
    ushort4 u = *(const ushort4*)&h[(size_t)s * 64 + qfo];
    acc.x += bf2f(u.x); acc.y += bf2f(u.y);
    acc.z += bf2f(u.z); acc.w += bf2f(u.w);
  }
  if (eo < end - i) {
    int s = col[i + eo];
    ushort4 u = *(const ushort4*)&h[(size_t)s * 64 + qfo];
    acc.x += bf2f(u.x); acc.y += bf2f(u.y);
    acc.z += bf2f(u.z); acc.w += bf2f(u.w);
  }
  return acc;
}

// ---------------------------------------------------------------------------
// fused gather1 + gemm2: block = 64-node tile. 4 waves gather 16 nodes each
// into the LDS A-tile (relu post-reduction), then 4x4 register GEMM. h2 bf16.
__global__ __launch_bounds__(256) void gather_gemm2(
    const unsigned short* __restrict__ h1, const int* __restrict__ row_ptr,
    const int* __restrict__ col, const float* __restrict__ W2,
    unsigned short* __restrict__ h2) {
  __shared__ float sX[64 * 68];          // 64 rows x 64 k, pad +4
  __shared__ float sW[64 * 64];
  const int tid = threadIdx.x;
  const int row0 = blockIdx.x * 64;
  const int lane = tid & 63, w = tid >> 6;
  const int eo = lane >> 4, qfo = (lane & 15) << 2;

#pragma unroll
  for (int i = 0; i < 16; i++) sW[i * 256 + tid] = W2[i * 256 + tid];

  for (int ni = 0; ni < 16; ni++) {
    int node = row0 + w * 16 + ni;
    float4 acc = make_float4(0.f, 0.f, 0.f, 0.f);
    if (node < N_NODES) {
      int i0 = row_ptr[node], e0 = row_ptr[node + 1];
      acc = gather_node_bf(h1, col, i0, e0, eo, qfo, acc);
    }
#pragma unroll
    for (int m = 16; m <= 32; m <<= 1) {
      acc.x += __shfl_xor(acc.x, m, 64);
      acc.y += __shfl_xor(acc.y, m, 64);
      acc.z += __shfl_xor(acc.z, m, 64);
      acc.w += __shfl_xor(acc.w, m, 64);
    }
    if (eo == 0) {                        // relu = layer-1 activation
      acc.x = fmaxf(acc.x, 0.f); acc.y = fmaxf(acc.y, 0.f);
      acc.z = fmaxf(acc.z, 0.f); acc.w = fmaxf(acc.w, 0.f);
      *(float4*)&sX[(w * 16 + ni) * 68 + qfo] = acc;
    }
  }
  __syncthreads();

  const int tx = tid & 15, ty = tid >> 4;
  float acc[4][4] = {};
#pragma unroll 4
  for (int k = 0; k < 64; k += 4) {
    float4 wv[4];
#pragma unroll
    for (int kk = 0; kk < 4; kk++)
      wv[kk] = *(const float4*)&sW[(k + kk) * 64 + tx * 4];
#pragma unroll
    for (int r = 0; r < 4; r++) {
      float4 xv = *(const float4*)&sX[(ty * 4 + r) * 68 + k];
      const float xs[4] = {xv.x, xv.y, xv.z, xv.w};
#pragma unroll
      for (int kk = 0; kk < 4; kk++) {
        acc[r][0] += xs[kk] * wv[kk].x;
        acc[r][1] += xs[kk] * wv[kk].y;
        acc[r][2] += xs[kk] * wv[kk].z;
        acc[r][3] += xs[kk] * wv[kk].w;
      }
    }
  }
#pragma unroll
  for (int r = 0; r < 4; r++) {
    int gr = row0 + ty * 4 + r;
    if (gr < N_NODES) {
      ushort4 u;
      u.x = f2bf(acc[r][0]); u.y = f2bf(acc[r][1]);
      u.z = f2bf(acc[r][2]); u.w = f2bf(acc[r][3]);
      *(ushort4*)&h2[(size_t)gr * 64 + tx * 4] = u;
    }
  }
}

// ---------------------------------------------------------------------------
// layer-2 aggregate, node-parallel (12500 blocks for latency hiding).
__global__ __launch_bounds__(256) void gather_sum(const unsigned short* __restrict__ h,
                                                  const int* __restrict__ row_ptr,
                                                  const int* __restrict__ col,
                                                  float* __restrict__ out) {
  int node = blockIdx.x * 4 + (threadIdx.x >> 6);
  if (node >= N_NODES) return;
  int lane = threadIdx.x & 63;
  int eo = lane >> 4, qfo = (lane & 15) << 2;
  int i = row_ptr[node];
  const int end = row_ptr[node + 1];

  float4 acc = gather_node_bf(h, col, i, end, eo, qfo,
                              make_float4(0.f, 0.f, 0.f, 0.f));
#pragma unroll
  for (int m = 16; m <= 32; m <<= 1) {
    acc.x += __shfl_xor(acc.x, m, 64);
    acc.y += __shfl_xor(acc.y, m, 64);
    acc.z += __shfl_xor(acc.z, m, 64);
    acc.w += __shfl_xor(acc.w, m, 64);
  }
  if (eo == 0) *(float4*)&out[(size_t)node * 64 + qfo] = acc;
}

// ---------------------------------------------------------------------------
// batch is SORTED -> contiguous segment per graph. 4 waves split the rows.
__global__ __launch_bounds__(256) void pool_fc(const float* __restrict__ agg,
                                               const int* __restrict__ batch,
                                               const float* __restrict__ Wfc,
                                               float* __restrict__ out) {
  __shared__ float sacc[4][64];
  int g = blockIdx.x;
  int tid = threadIdx.x, lane = tid & 63, w = tid >> 6;

  int lo = 0, hi = N_NODES;
  while (lo < hi) { int mid = (lo + hi) >> 1; if (batch[mid] < g) lo = mid + 1; else hi = mid; }
  const int start = lo;
  hi = N_NODES;
  while (lo < hi) { int mid = (lo + hi) >> 1; if (batch[mid] < g + 1) lo = mid + 1; else hi = mid; }
  const int end = lo;

  float acc = 0.f;
  for (int n = start + w; n < end; n += 4) acc += agg[(size_t)n * 64 + lane];
  sacc[w][lane] = acc;
  __syncthreads();
  if (w == 0) {
    float v = sacc[0][lane] + sacc[1][lane] + sacc[2][lane] + sacc[3][lane];
    v /= fmaxf((float)(end - start), 1.f);
    v *= Wfc[lane];
#pragma unroll
    for (int off = 32; off; off >>= 1) v += __shfl_down(v, off, 64);
    if (lane == 0) out[g] = 1.f / (1.f + expf(-v));
  }
}

// ---------------------------------------------------------------------------
extern "C" void kernel_launch(void* const* d_in, const int* in_sizes, int n_in,
                              void* d_out, int out_size, void* d_ws, size_t ws_size,
                              hipStream_t stream) {
  const float* x     = (const float*)d_in[0];
  const int*   ei    = (const int*)d_in[1];   // [2, E]: src then dst
  const int*   batch = (const int*)d_in[2];
  const float* W1    = (const float*)d_in[3];
  const float* W2    = (const float*)d_in[4];
  const float* Wfc   = (const float*)d_in[5];
  float*       out   = (float*)d_out;

  const int* src = ei;
  const int* dst = ei + N_EDGES;

  // workspace layout (~29.0 MB). ebuf/cnt/partials alias the agg region:
  // they are dead before gather_sum writes agg.
  char* ws = (char*)d_ws;
  unsigned short* h1 = (unsigned short*)(ws);                  // [N,64] bf16
  unsigned short* h2 = h1 + (size_t)N_NODES * DIM;             // [N,64] bf16
  float* agg = (float*)(ws + (size_t)N_NODES * DIM * 4);       // [N,64] fp32
  unsigned int* ebuf = (unsigned int*)agg;                     // [E] (alias)
  int*   cnt      = (int*)(ebuf + N_EDGES);                    // [NCNT] (alias)
  int*   partials = cnt + NCNT;                                // [P2_NBLK] (alias)
  int*   col        = (int*)(ws + (size_t)N_NODES * DIM * 8);  // [E]
  int*   row_ptr    = col + N_EDGES;                           // [N+1]
  int*   bucket_ptr = row_ptr + N_NODES + 1;                   // [NBKT+1]

  // dispatch 1: gemm1 (h1 = bf16(x@W1)) || bucket histogram
  gemm1_bhist<<<GGRID + BH_BLK, 256, 0, stream>>>(x, W1, h1, dst, cnt);

  // exclusive scan of count matrix -> per-(bucket,block) offsets + bucket_ptr
  psum512<<<P2_NBLK, 512, 0, stream>>>(cnt, partials);
  scan_partials<<<1, 256, 0, stream>>>(partials);
  sblocks512<<<P2_NBLK, 512, 0, stream>>>(cnt, partials, bucket_ptr);

  // bucket-sorted edge buffer, then exact per-node CSR (coalesced writes)
  bscatter<<<BH_BLK, 256, 0, stream>>>(src, dst, cnt, ebuf);
  bucket_to_csr<<<NBKT, 256, 0, stream>>>(ebuf, bucket_ptr, row_ptr, col);

  // layer 1 aggregate + relu + gemm2 (fused): h2 = bf16(relu(agg1) @ W2)
  gather_gemm2<<<GGRID, 256, 0, stream>>>(h1, row_ptr, col, W2, h2);

  // layer 2 aggregate (node-parallel), then mean-pool + FC + sigmoid
  gather_sum<<<(N_NODES + 3) / 4, 256, 0, stream>>>(h2, row_ptr, col, agg);
  pool_fc<<<N_GRAPHS, 256, 0, stream>>>(agg, batch, Wfc, out);
}

// Round 9
// 193.982 us; speedup vs baseline: 4.2660x; 1.1294x over previous
//
#include <hip/hip_runtime.h>
#include <cmath>

#define N_NODES 50000
#define N_EDGES 800000
#define N_FEAT 128
#define DIM 64
#define N_GRAPHS 512
#define GGRID ((N_NODES + 63) / 64)         // 782 gemm1 tiles / buckets
#define NBKT GGRID                          // bucket = dst>>6
#define BH_BLK 128                          // bucket-sort blocks
#define EPB (N_EDGES / BH_BLK)              // 6250 edges per sort block
#define NCNT (NBKT * BH_BLK)                // 100096 count-matrix entries
#define P2_NBLK ((NCNT + 511) / 512)        // 196 scan blocks

// bf16 storage helpers (RNE). Storage-only: all math in fp32.
__device__ __forceinline__ unsigned short f2bf(float f) {
  union { float f; unsigned int u; } v; v.f = f;
  return (unsigned short)((v.u + 0x7FFFu + ((v.u >> 16) & 1u)) >> 16);
}
__device__ __forceinline__ float bf2f(unsigned short u) {
  union { unsigned int u; float f; } v; v.u = (unsigned int)u << 16;
  return v.f;
}

// ---------------------------------------------------------------------------
// per-block bucket histogram of dst>>6; cnt bucket-major: cnt[b*BH_BLK + k]
__global__ __launch_bounds__(256) void bhist(const int* __restrict__ dst,
                                             int* __restrict__ cnt) {
  __shared__ int lh[NBKT];
  const int tid = threadIdx.x, k = blockIdx.x;
  for (int i = tid; i < NBKT; i += 256) lh[i] = 0;
  __syncthreads();
  const int base = k * EPB;
  for (int j = tid; j < EPB; j += 256)
    atomicAdd(&lh[dst[base + j] >> 6], 1);
  __syncthreads();
  for (int i = tid; i < NBKT; i += 256) cnt[i * BH_BLK + k] = lh[i];
}

// ---------------------------------------------------------------------------
// hierarchical exclusive scan over cnt[NCNT] (in-place) + bucket_ptr extract
__global__ __launch_bounds__(512) void psum512(const int* __restrict__ cnt,
                                               int* __restrict__ partials) {
  __shared__ int ws[8];
  int gid = blockIdx.x * 512 + threadIdx.x;
  int v = (gid < NCNT) ? cnt[gid] : 0;
#pragma unroll
  for (int off = 32; off; off >>= 1) v += __shfl_down(v, off, 64);
  int lane = threadIdx.x & 63, w = threadIdx.x >> 6;
  if (lane == 0) ws[w] = v;
  __syncthreads();
  if (threadIdx.x == 0) {
    int s = 0;
#pragma unroll
    for (int i = 0; i < 8; i++) s += ws[i];
    partials[blockIdx.x] = s;
  }
}

__global__ __launch_bounds__(256) void scan_partials(int* __restrict__ partials) {
  __shared__ int buf[256];
  int tid = threadIdx.x;
  int v = (tid < P2_NBLK) ? partials[tid] : 0;
  buf[tid] = v;
  __syncthreads();
  for (int off = 1; off < 256; off <<= 1) {
    int t = (tid >= off) ? buf[tid - off] : 0;
    __syncthreads();
    buf[tid] += t;
    __syncthreads();
  }
  if (tid < P2_NBLK) partials[tid] = buf[tid] - v;   // exclusive
}

__global__ __launch_bounds__(512) void sblocks512(int* __restrict__ cnt,
                                                  const int* __restrict__ partials,
                                                  int* __restrict__ bucket_ptr) {
  __shared__ int buf[512];
  int tid = threadIdx.x;
  int gid = blockIdx.x * 512 + tid;
  int v = (gid < NCNT) ? cnt[gid] : 0;
  buf[tid] = v;
  __syncthreads();
  for (int off = 1; off < 512; off <<= 1) {
    int t = (tid >= off) ? buf[tid - off] : 0;
    __syncthreads();
    buf[tid] += t;
    __syncthreads();
  }
  int excl = buf[tid] - v + partials[blockIdx.x];
  if (gid < NCNT) {
    cnt[gid] = excl;                                  // in-place offsets
    if ((gid & (BH_BLK - 1)) == 0) bucket_ptr[gid / BH_BLK] = excl;
    if (gid == NCNT - 1) bucket_ptr[NBKT] = excl + v; // == N_EDGES
  }
}

// ---------------------------------------------------------------------------
// GEMM body for gemm1: out[M][64] = A[M][128] @ W[128][64], bf16 output rows.
template<int K>
__device__ __forceinline__ void gemm_body_bf(const float* __restrict__ A,
                                             const float* __restrict__ W,
                                             unsigned short* __restrict__ out,
                                             int M, int row0, int tid,
                                             float* sX, float* sW) {
  const int tx = tid & 15, ty = tid >> 4;
  const int q = tid & 7, r0 = tid >> 3;
  float acc[4][4] = {};

  for (int kb = 0; kb < K; kb += 32) {
    __syncthreads();
    if ((kb & 63) == 0) {
#pragma unroll
      for (int i = 0; i < 16; i++)
        sW[i * 256 + tid] = W[kb * 64 + i * 256 + tid];
    }
#pragma unroll
    for (int rr = 0; rr < 64; rr += 32) {
      int r = r0 + rr;
      int gr = row0 + r;
      float4 v = make_float4(0.f, 0.f, 0.f, 0.f);
      if (gr < M) v = *(const float4*)&A[(size_t)gr * K + kb + q * 4];
      *(float4*)&sX[r * 36 + q * 4] = v;
    }
    __syncthreads();

    const int kw = kb & 63;
#pragma unroll 4
    for (int k = 0; k < 32; k += 4) {
      float4 wv[4];
#pragma unroll
      for (int kk = 0; kk < 4; kk++)
        wv[kk] = *(const float4*)&sW[(kw + k + kk) * 64 + tx * 4];
#pragma unroll
      for (int r = 0; r < 4; r++) {
        float4 xv = *(const float4*)&sX[(ty * 4 + r) * 36 + k];
        const float xs[4] = {xv.x, xv.y, xv.z, xv.w};
#pragma unroll
        for (int kk = 0; kk < 4; kk++) {
          acc[r][0] += xs[kk] * wv[kk].x;
          acc[r][1] += xs[kk] * wv[kk].y;
          acc[r][2] += xs[kk] * wv[kk].z;
          acc[r][3] += xs[kk] * wv[kk].w;
        }
      }
    }
  }

#pragma unroll
  for (int r = 0; r < 4; r++) {
    int gr = row0 + ty * 4 + r;
    if (gr < M) {
      ushort4 u;
      u.x = f2bf(acc[r][0]); u.y = f2bf(acc[r][1]);
      u.z = f2bf(acc[r][2]); u.w = f2bf(acc[r][3]);
      *(ushort4*)&out[(size_t)gr * 64 + tx * 4] = u;
    }
  }
}

// fused: blocks [0,GGRID) = gemm1 (x@W1 -> h1 bf16); blocks [GGRID..) run
// bscatter (needs cnt offsets, which are ready; gemm1 hides the scatter).
__global__ __launch_bounds__(256) void gemm1_bscatter(
    const float* __restrict__ x, const float* __restrict__ W1,
    unsigned short* __restrict__ h1, const int* __restrict__ src,
    const int* __restrict__ dst, const int* __restrict__ cnt,
    unsigned int* __restrict__ ebuf) {
  __shared__ float sX[64 * 36];
  __shared__ float sW[64 * 64];
  const int tid = threadIdx.x;
  if (blockIdx.x < GGRID) {
    gemm_body_bf<N_FEAT>(x, W1, h1, N_NODES, blockIdx.x * 64, tid, sX, sW);
  } else {
    int* loff = (int*)sX;                     // 782 ints fit easily
    const int k = blockIdx.x - GGRID;
    for (int i = tid; i < NBKT; i += 256) loff[i] = cnt[i * BH_BLK + k];
    __syncthreads();
    const int base = k * EPB;
    for (int j = tid; j < EPB; j += 256) {
      int e = base + j;
      int d = dst[e];
      int pos = atomicAdd(&loff[d >> 6], 1);
      ebuf[pos] = ((unsigned int)src[e] << 6) | (unsigned int)(d & 63);
    }
  }
}

// ---------------------------------------------------------------------------
// per bucket: 64-entry dst_local histogram -> row_ptr, then redistribute
// ebuf[p0..p1) into exact per-node CSR order in col[p0..p1).
__global__ __launch_bounds__(256) void bucket_to_csr(
    const unsigned int* __restrict__ ebuf, const int* __restrict__ bucket_ptr,
    int* __restrict__ row_ptr, int* __restrict__ col) {
  __shared__ int lh[64];
  __shared__ int loff[64];
  const int b = blockIdx.x, tid = threadIdx.x;
  const int p0 = bucket_ptr[b], p1 = bucket_ptr[b + 1];

  if (tid < 64) lh[tid] = 0;
  __syncthreads();
  for (int i = p0 + tid; i < p1; i += 256)
    atomicAdd(&lh[ebuf[i] & 63], 1);
  __syncthreads();

  if (tid < 64) {                       // wave-0 exclusive scan of 64 degrees
    int v = lh[tid];
    int s = v;
#pragma unroll
    for (int off = 1; off < 64; off <<= 1) {
      int t = __shfl_up(s, off, 64);
      if (tid >= off) s += t;
    }
    int excl = s - v;
    loff[tid] = excl;
    int gid = b * 64 + tid;
    if (gid <= N_NODES) row_ptr[gid] = p0 + excl;
  }
  __syncthreads();

  for (int i = p0 + tid; i < p1; i += 256) {
    unsigned int u = ebuf[i];
    int pos = atomicAdd(&loff[u & 63], 1);
    col[p0 + pos] = (int)(u >> 6);
  }
}

// ---------------------------------------------------------------------------
// per-node gather partial over bf16 rows: lane = (eo 0..3, qfo quad*4).
// 16-edge unroll = 4 independent row loads per lane in flight.
__device__ __forceinline__ float4 gather_node_bf(const unsigned short* __restrict__ h,
                                                 const int* __restrict__ col,
                                                 int i, int end, int eo, int qfo,
                                                 float4 acc) {
  for (; i + 16 <= end; i += 16) {
    int s0 = col[i + eo];
    int s1 = col[i + 4 + eo];
    int s2 = col[i + 8 + eo];
    int s3 = col[i + 12 + eo];
    ushort4 u0 = *(const ushort4*)&h[(size_t)s0 * 64 + qfo];
    ushort4 u1 = *(const ushort4*)&h[(size_t)s1 * 64 + qfo];
    ushort4 u2 = *(const ushort4*)&h[(size_t)s2 * 64 + qfo];
    ushort4 u3 = *(const ushort4*)&h[(size_t)s3 * 64 + qfo];
    acc.x += (bf2f(u0.x) + bf2f(u1.x)) + (bf2f(u2.x) + bf2f(u3.x));
    acc.y += (bf2f(u0.y) + bf2f(u1.y)) + (bf2f(u2.y) + bf2f(u3.y));
    acc.z += (bf2f(u0.z) + bf2f(u1.z)) + (bf2f(u2.z) + bf2f(u3.z));
    acc.w += (bf2f(u0.w) + bf2f(u1.w)) + (bf2f(u2.w) + bf2f(u3.w));
  }
  for (; i + 4 <= end; i += 4) {
    int s = col[i + eo];
    ushort4 u = *(const ushort4*)&h[(size_t)s * 64 + qfo];
    acc.x += bf2f(u.x); acc.y += bf2f(u.y);
    acc.z += bf2f(u.z); acc.w += bf2f(u.w);
  }
  if (eo < end - i) {
    int s = col[i + eo];
    ushort4 u = *(const ushort4*)&h[(size_t)s * 64 + qfo];
    acc.x += bf2f(u.x); acc.y += bf2f(u.y);
    acc.z += bf2f(u.z); acc.w += bf2f(u.w);
  }
  return acc;
}

// ---------------------------------------------------------------------------
// fused gather1 + relu + gemm2, 1024 threads: 16 waves gather 4 nodes each
// into the LDS A-tile (4x the waves of the 256-thread version -> occupancy),
// then a 32x32-thread 2x2-register GEMM. h2 bf16.
__global__ __launch_bounds__(1024, 8) void gather_gemm2(
    const unsigned short* __restrict__ h1, const int* __restrict__ row_ptr,
    const int* __restrict__ col, const float* __restrict__ W2,
    unsigned short* __restrict__ h2) {
  __shared__ float sX[64 * 68];          // 64 rows x 64 k, pad +4
  __shared__ float sW[64 * 64];
  const int tid = threadIdx.x;
  const int row0 = blockIdx.x * 64;
  const int lane = tid & 63, w = tid >> 6;       // 16 waves
  const int eo = lane >> 4, qfo = (lane & 15) << 2;

#pragma unroll
  for (int i = 0; i < 4; i++) sW[i * 1024 + tid] = W2[i * 1024 + tid];

#pragma unroll
  for (int ni = 0; ni < 4; ni++) {
    int r = ni * 16 + w;                         // this wave's tile row
    int node = row0 + r;
    float4 acc = make_float4(0.f, 0.f, 0.f, 0.f);
    if (node < N_NODES)
      acc = gather_node_bf(h1, col, row_ptr[node], row_ptr[node + 1], eo, qfo, acc);
#pragma unroll
    for (int m = 16; m <= 32; m <<= 1) {
      acc.x += __shfl_xor(acc.x, m, 64);
      acc.y += __shfl_xor(acc.y, m, 64);
      acc.z += __shfl_xor(acc.z, m, 64);
      acc.w += __shfl_xor(acc.w, m, 64);
    }
    if (eo == 0) {                               // relu = layer-1 activation
      acc.x = fmaxf(acc.x, 0.f); acc.y = fmaxf(acc.y, 0.f);
      acc.z = fmaxf(acc.z, 0.f); acc.w = fmaxf(acc.w, 0.f);
      *(float4*)&sX[r * 68 + qfo] = acc;
    }
  }
  __syncthreads();

  // 32x32 threads, 2 rows x 2 cols each
  const int tx = tid & 31, ty = tid >> 5;
  float a00 = 0.f, a01 = 0.f, a10 = 0.f, a11 = 0.f;
#pragma unroll 4
  for (int k = 0; k < 64; k += 4) {
    float4 x0 = *(const float4*)&sX[(ty * 2) * 68 + k];
    float4 x1 = *(const float4*)&sX[(ty * 2 + 1) * 68 + k];
    float2 w0 = *(const float2*)&sW[(k + 0) * 64 + tx * 2];
    float2 w1 = *(const float2*)&sW[(k + 1) * 64 + tx * 2];
    float2 w2 = *(const float2*)&sW[(k + 2) * 64 + tx * 2];
    float2 w3 = *(const float2*)&sW[(k + 3) * 64 + tx * 2];
    a00 += x0.x * w0.x + x0.y * w1.x + x0.z * w2.x + x0.w * w3.x;
    a01 += x0.x * w0.y + x0.y * w1.y + x0.z * w2.y + x0.w * w3.y;
    a10 += x1.x * w0.x + x1.y * w1.x + x1.z * w2.x + x1.w * w3.x;
    a11 += x1.x * w0.y + x1.y * w1.y + x1.z * w2.y + x1.w * w3.y;
  }
  int gr0 = row0 + ty * 2, gr1 = gr0 + 1;
  if (gr0 < N_NODES) {
    ushort2 u; u.x = f2bf(a00); u.y = f2bf(a01);
    *(ushort2*)&h2[(size_t)gr0 * 64 + tx * 2] = u;
  }
  if (gr1 < N_NODES) {
    ushort2 u; u.x = f2bf(a10); u.y = f2bf(a11);
    *(ushort2*)&h2[(size_t)gr1 * 64 + tx * 2] = u;
  }
}

// ---------------------------------------------------------------------------
// layer-2 aggregate, node-parallel (12500 blocks for latency hiding).
__global__ __launch_bounds__(256) void gather_sum(const unsigned short* __restrict__ h,
                                                  const int* __restrict__ row_ptr,
                                                  const int* __restrict__ col,
                                                  float* __restrict__ out) {
  int node = blockIdx.x * 4 + (threadIdx.x >> 6);
  if (node >= N_NODES) return;
  int lane = threadIdx.x & 63;
  int eo = lane >> 4, qfo = (lane & 15) << 2;

  float4 acc = gather_node_bf(h, col, row_ptr[node], row_ptr[node + 1], eo, qfo,
                              make_float4(0.f, 0.f, 0.f, 0.f));
#pragma unroll
  for (int m = 16; m <= 32; m <<= 1) {
    acc.x += __shfl_xor(acc.x, m, 64);
    acc.y += __shfl_xor(acc.y, m, 64);
    acc.z += __shfl_xor(acc.z, m, 64);
    acc.w += __shfl_xor(acc.w, m, 64);
  }
  if (eo == 0) *(float4*)&out[(size_t)node * 64 + qfo] = acc;
}

// ---------------------------------------------------------------------------
// batch is SORTED -> contiguous segment per graph. 4 waves split the rows.
__global__ __launch_bounds__(256) void pool_fc(const float* __restrict__ agg,
                                               const int* __restrict__ batch,
                                               const float* __restrict__ Wfc,
                                               float* __restrict__ out) {
  __shared__ float sacc[4][64];
  int g = blockIdx.x;
  int tid = threadIdx.x, lane = tid & 63, w = tid >> 6;

  int lo = 0, hi = N_NODES;
  while (lo < hi) { int mid = (lo + hi) >> 1; if (batch[mid] < g) lo = mid + 1; else hi = mid; }
  const int start = lo;
  hi = N_NODES;
  while (lo < hi) { int mid = (lo + hi) >> 1; if (batch[mid] < g + 1) lo = mid + 1; else hi = mid; }
  const int end = lo;

  float acc = 0.f;
  for (int n = start + w; n < end; n += 4) acc += agg[(size_t)n * 64 + lane];
  sacc[w][lane] = acc;
  __syncthreads();
  if (w == 0) {
    float v = sacc[0][lane] + sacc[1][lane] + sacc[2][lane] + sacc[3][lane];
    v /= fmaxf((float)(end - start), 1.f);
    v *= Wfc[lane];
#pragma unroll
    for (int off = 32; off; off >>= 1) v += __shfl_down(v, off, 64);
    if (lane == 0) out[g] = 1.f / (1.f + expf(-v));
  }
}

// ---------------------------------------------------------------------------
extern "C" void kernel_launch(void* const* d_in, const int* in_sizes, int n_in,
                              void* d_out, int out_size, void* d_ws, size_t ws_size,
                              hipStream_t stream) {
  const float* x     = (const float*)d_in[0];
  const int*   ei    = (const int*)d_in[1];   // [2, E]: src then dst
  const int*   batch = (const int*)d_in[2];
  const float* W1    = (const float*)d_in[3];
  const float* W2    = (const float*)d_in[4];
  const float* Wfc   = (const float*)d_in[5];
  float*       out   = (float*)d_out;

  const int* src = ei;
  const int* dst = ei + N_EDGES;

  // workspace layout (~29.0 MB). ebuf/cnt/partials alias the agg region:
  // dead before gather_sum writes agg.
  char* ws = (char*)d_ws;
  unsigned short* h1 = (unsigned short*)(ws);                  // [N,64] bf16
  unsigned short* h2 = h1 + (size_t)N_NODES * DIM;             // [N,64] bf16
  float* agg = (float*)(ws + (size_t)N_NODES * DIM * 4);       // [N,64] fp32
  unsigned int* ebuf = (unsigned int*)agg;                     // [E] (alias)
  int*   cnt      = (int*)(ebuf + N_EDGES);                    // [NCNT] (alias)
  int*   partials = cnt + NCNT;                                // [P2_NBLK] (alias)
  int*   col        = (int*)(ws + (size_t)N_NODES * DIM * 8);  // [E]
  int*   row_ptr    = col + N_EDGES;                           // [N+1]
  int*   bucket_ptr = row_ptr + N_NODES + 1;                   // [NBKT+1]

  // CSR front half: histogram -> scan
  bhist<<<BH_BLK, 256, 0, stream>>>(dst, cnt);
  psum512<<<P2_NBLK, 512, 0, stream>>>(cnt, partials);
  scan_partials<<<1, 256, 0, stream>>>(partials);
  sblocks512<<<P2_NBLK, 512, 0, stream>>>(cnt, partials, bucket_ptr);

  // gemm1 (h1 = bf16(x@W1)) || bucket-sorted edge scatter
  gemm1_bscatter<<<GGRID + BH_BLK, 256, 0, stream>>>(x, W1, h1, src, dst, cnt, ebuf);
  bucket_to_csr<<<NBKT, 256, 0, stream>>>(ebuf, bucket_ptr, row_ptr, col);

  // layer 1 aggregate + relu + gemm2 (fused, 16 waves/block)
  gather_gemm2<<<GGRID, 1024, 0, stream>>>(h1, row_ptr, col, W2, h2);

  // layer 2 aggregate (node-parallel), then mean-pool + FC + sigmoid
  gather_sum<<<(N_NODES + 3) / 4, 256, 0, stream>>>(h2, row_ptr, col, agg);
  pool_fc<<<N_GRAPHS, 256, 0, stream>>>(agg, batch, Wfc, out);
}

// Round 10
// 160.263 us; speedup vs baseline: 5.1636x; 1.2104x over previous
//
#include <hip/hip_runtime.h>
#include <cmath>

#define N_NODES 50000
#define N_EDGES 800000
#define N_FEAT 128
#define DIM 64
#define N_GRAPHS 512
#define GGRID ((N_NODES + 63) / 64)         // 782 gemm1 tiles / buckets
#define NBKT GGRID                          // bucket = dst>>6
#define BH_BLK 128                          // bucket-sort blocks
#define EPB (N_EDGES / BH_BLK)              // 6250 edges per sort block
#define NCNT (NBKT * BH_BLK)                // 100096 count-matrix entries
#define P2_NBLK ((NCNT + 511) / 512)        // 196 scan blocks

// bf16 storage helpers (RNE). Storage-only: all math in fp32.
__device__ __forceinline__ unsigned short f2bf(float f) {
  union { float f; unsigned int u; } v; v.f = f;
  return (unsigned short)((v.u + 0x7FFFu + ((v.u >> 16) & 1u)) >> 16);
}
__device__ __forceinline__ float bf2f(unsigned short u) {
  union { unsigned int u; float f; } v; v.u = (unsigned int)u << 16;
  return v.f;
}

// ---------------------------------------------------------------------------
// w2fc[k] = sum_j W2[k][j] * Wfc[j]  (collapses gemm2+FC into one 64-vector)
__global__ __launch_bounds__(64) void make_w2fc(const float* __restrict__ W2,
                                                const float* __restrict__ Wfc,
                                                float* __restrict__ w2fc) {
  int k = threadIdx.x;
  float s = 0.f;
#pragma unroll 8
  for (int j = 0; j < 64; j++) s += W2[k * 64 + j] * Wfc[j];
  w2fc[k] = s;
}

// ---------------------------------------------------------------------------
// per-block bucket histogram of dst>>6; cnt bucket-major: cnt[b*BH_BLK + k]
__global__ __launch_bounds__(256) void bhist(const int* __restrict__ dst,
                                             int* __restrict__ cnt) {
  __shared__ int lh[NBKT];
  const int tid = threadIdx.x, k = blockIdx.x;
  for (int i = tid; i < NBKT; i += 256) lh[i] = 0;
  __syncthreads();
  const int base = k * EPB;
  for (int j = tid; j < EPB; j += 256)
    atomicAdd(&lh[dst[base + j] >> 6], 1);
  __syncthreads();
  for (int i = tid; i < NBKT; i += 256) cnt[i * BH_BLK + k] = lh[i];
}

// ---------------------------------------------------------------------------
// hierarchical exclusive scan over cnt[NCNT] (in-place) + bucket_ptr extract
__global__ __launch_bounds__(512) void psum512(const int* __restrict__ cnt,
                                               int* __restrict__ partials) {
  __shared__ int ws[8];
  int gid = blockIdx.x * 512 + threadIdx.x;
  int v = (gid < NCNT) ? cnt[gid] : 0;
#pragma unroll
  for (int off = 32; off; off >>= 1) v += __shfl_down(v, off, 64);
  int lane = threadIdx.x & 63, w = threadIdx.x >> 6;
  if (lane == 0) ws[w] = v;
  __syncthreads();
  if (threadIdx.x == 0) {
    int s = 0;
#pragma unroll
    for (int i = 0; i < 8; i++) s += ws[i];
    partials[blockIdx.x] = s;
  }
}

__global__ __launch_bounds__(256) void scan_partials(int* __restrict__ partials) {
  __shared__ int buf[256];
  int tid = threadIdx.x;
  int v = (tid < P2_NBLK) ? partials[tid] : 0;
  buf[tid] = v;
  __syncthreads();
  for (int off = 1; off < 256; off <<= 1) {
    int t = (tid >= off) ? buf[tid - off] : 0;
    __syncthreads();
    buf[tid] += t;
    __syncthreads();
  }
  if (tid < P2_NBLK) partials[tid] = buf[tid] - v;   // exclusive
}

__global__ __launch_bounds__(512) void sblocks512(int* __restrict__ cnt,
                                                  const int* __restrict__ partials,
                                                  int* __restrict__ bucket_ptr) {
  __shared__ int buf[512];
  int tid = threadIdx.x;
  int gid = blockIdx.x * 512 + tid;
  int v = (gid < NCNT) ? cnt[gid] : 0;
  buf[tid] = v;
  __syncthreads();
  for (int off = 1; off < 512; off <<= 1) {
    int t = (tid >= off) ? buf[tid - off] : 0;
    __syncthreads();
    buf[tid] += t;
    __syncthreads();
  }
  int excl = buf[tid] - v + partials[blockIdx.x];
  if (gid < NCNT) {
    cnt[gid] = excl;                                  // in-place offsets
    if ((gid & (BH_BLK - 1)) == 0) bucket_ptr[gid / BH_BLK] = excl;
    if (gid == NCNT - 1) bucket_ptr[NBKT] = excl + v; // == N_EDGES
  }
}

// ---------------------------------------------------------------------------
// GEMM body for gemm1: out[M][64] = A[M][128] @ W[128][64], bf16 output rows.
template<int K>
__device__ __forceinline__ void gemm_body_bf(const float* __restrict__ A,
                                             const float* __restrict__ W,
                                             unsigned short* __restrict__ out,
                                             int M, int row0, int tid,
                                             float* sX, float* sW) {
  const int tx = tid & 15, ty = tid >> 4;
  const int q = tid & 7, r0 = tid >> 3;
  float acc[4][4] = {};

  for (int kb = 0; kb < K; kb += 32) {
    __syncthreads();
    if ((kb & 63) == 0) {
#pragma unroll
      for (int i = 0; i < 16; i++)
        sW[i * 256 + tid] = W[kb * 64 + i * 256 + tid];
    }
#pragma unroll
    for (int rr = 0; rr < 64; rr += 32) {
      int r = r0 + rr;
      int gr = row0 + r;
      float4 v = make_float4(0.f, 0.f, 0.f, 0.f);
      if (gr < M) v = *(const float4*)&A[(size_t)gr * K + kb + q * 4];
      *(float4*)&sX[r * 36 + q * 4] = v;
    }
    __syncthreads();

    const int kw = kb & 63;
#pragma unroll 4
    for (int k = 0; k < 32; k += 4) {
      float4 wv[4];
#pragma unroll
      for (int kk = 0; kk < 4; kk++)
        wv[kk] = *(const float4*)&sW[(kw + k + kk) * 64 + tx * 4];
#pragma unroll
      for (int r = 0; r < 4; r++) {
        float4 xv = *(const float4*)&sX[(ty * 4 + r) * 36 + k];
        const float xs[4] = {xv.x, xv.y, xv.z, xv.w};
#pragma unroll
        for (int kk = 0; kk < 4; kk++) {
          acc[r][0] += xs[kk] * wv[kk].x;
          acc[r][1] += xs[kk] * wv[kk].y;
          acc[r][2] += xs[kk] * wv[kk].z;
          acc[r][3] += xs[kk] * wv[kk].w;
        }
      }
    }
  }

#pragma unroll
  for (int r = 0; r < 4; r++) {
    int gr = row0 + ty * 4 + r;
    if (gr < M) {
      ushort4 u;
      u.x = f2bf(acc[r][0]); u.y = f2bf(acc[r][1]);
      u.z = f2bf(acc[r][2]); u.w = f2bf(acc[r][3]);
      *(ushort4*)&out[(size_t)gr * 64 + tx * 4] = u;
    }
  }
}

// fused: blocks [0,GGRID) = gemm1 (x@W1 -> h1 bf16); blocks [GGRID..) run
// the bucket scatter (cnt offsets ready; gemm1 hides the scatter cost).
__global__ __launch_bounds__(256) void gemm1_bscatter(
    const float* __restrict__ x, const float* __restrict__ W1,
    unsigned short* __restrict__ h1, const int* __restrict__ src,
    const int* __restrict__ dst, const int* __restrict__ cnt,
    unsigned int* __restrict__ ebuf) {
  __shared__ float sX[64 * 36];
  __shared__ float sW[64 * 64];
  const int tid = threadIdx.x;
  if (blockIdx.x < GGRID) {
    gemm_body_bf<N_FEAT>(x, W1, h1, N_NODES, blockIdx.x * 64, tid, sX, sW);
  } else {
    int* loff = (int*)sX;                     // 782 ints fit easily
    const int k = blockIdx.x - GGRID;
    for (int i = tid; i < NBKT; i += 256) loff[i] = cnt[i * BH_BLK + k];
    __syncthreads();
    const int base = k * EPB;
    for (int j = tid; j < EPB; j += 256) {
      int e = base + j;
      int d = dst[e];
      int pos = atomicAdd(&loff[d >> 6], 1);
      ebuf[pos] = ((unsigned int)src[e] << 6) | (unsigned int)(d & 63);
    }
  }
}

// ---------------------------------------------------------------------------
// per bucket: 64-entry dst_local histogram -> row_ptr, then redistribute
// ebuf[p0..p1) into exact per-node CSR order in col[p0..p1).
__global__ __launch_bounds__(256) void bucket_to_csr(
    const unsigned int* __restrict__ ebuf, const int* __restrict__ bucket_ptr,
    int* __restrict__ row_ptr, int* __restrict__ col) {
  __shared__ int lh[64];
  __shared__ int loff[64];
  const int b = blockIdx.x, tid = threadIdx.x;
  const int p0 = bucket_ptr[b], p1 = bucket_ptr[b + 1];

  if (tid < 64) lh[tid] = 0;
  __syncthreads();
  for (int i = p0 + tid; i < p1; i += 256)
    atomicAdd(&lh[ebuf[i] & 63], 1);
  __syncthreads();

  if (tid < 64) {                       // wave-0 exclusive scan of 64 degrees
    int v = lh[tid];
    int s = v;
#pragma unroll
    for (int off = 1; off < 64; off <<= 1) {
      int t = __shfl_up(s, off, 64);
      if (tid >= off) s += t;
    }
    int excl = s - v;
    loff[tid] = excl;
    int gid = b * 64 + tid;
    if (gid <= N_NODES) row_ptr[gid] = p0 + excl;
  }
  __syncthreads();

  for (int i = p0 + tid; i < p1; i += 256) {
    unsigned int u = ebuf[i];
    int pos = atomicAdd(&loff[u & 63], 1);
    col[p0 + pos] = (int)(u >> 6);
  }
}

// ---------------------------------------------------------------------------
// per-node gather partial over bf16 rows: lane = (eo 0..3, qfo quad*4).
// 16-edge unroll = 4 independent row loads per lane in flight.
__device__ __forceinline__ float4 gather_node_bf(const unsigned short* __restrict__ h,
                                                 const int* __restrict__ col,
                                                 int i, int end, int eo, int qfo,
                                                 float4 acc) {
  for (; i + 16 <= end; i += 16) {
    int s0 = col[i + eo];
    int s1 = col[i + 4 + eo];
    int s2 = col[i + 8 + eo];
    int s3 = col[i + 12 + eo];
    ushort4 u0 = *(const ushort4*)&h[(size_t)s0 * 64 + qfo];
    ushort4 u1 = *(const ushort4*)&h[(size_t)s1 * 64 + qfo];
    ushort4 u2 = *(const ushort4*)&h[(size_t)s2 * 64 + qfo];
    ushort4 u3 = *(const ushort4*)&h[(size_t)s3 * 64 + qfo];
    acc.x += (bf2f(u0.x) + bf2f(u1.x)) + (bf2f(u2.x) + bf2f(u3.x));
    acc.y += (bf2f(u0.y) + bf2f(u1.y)) + (bf2f(u2.y) + bf2f(u3.y));
    acc.z += (bf2f(u0.z) + bf2f(u1.z)) + (bf2f(u2.z) + bf2f(u3.z));
    acc.w += (bf2f(u0.w) + bf2f(u1.w)) + (bf2f(u2.w) + bf2f(u3.w));
  }
  for (; i + 4 <= end; i += 4) {
    int s = col[i + eo];
    ushort4 u = *(const ushort4*)&h[(size_t)s * 64 + qfo];
    acc.x += bf2f(u.x); acc.y += bf2f(u.y);
    acc.z += bf2f(u.z); acc.w += bf2f(u.w);
  }
  if (eo < end - i) {
    int s = col[i + eo];
    ushort4 u = *(const ushort4*)&h[(size_t)s * 64 + qfo];
    acc.x += bf2f(u.x); acc.y += bf2f(u.y);
    acc.z += bf2f(u.z); acc.w += bf2f(u.w);
  }
  return acc;
}

// ---------------------------------------------------------------------------
// layer-1 gather + relu + dot(w2fc) -> scalar z per node. Node-parallel
// (12500 blocks). Replaces gather_gemm2 + gather_sum: the layer-2 gather
// collapses to scalar z reads (algebra: pooled@Wfc distributes over edges).
__global__ __launch_bounds__(256) void gather_z(const unsigned short* __restrict__ h1,
                                                const int* __restrict__ row_ptr,
                                                const int* __restrict__ col,
                                                const float* __restrict__ w2fc,
                                                float* __restrict__ z) {
  int node = blockIdx.x * 4 + (threadIdx.x >> 6);
  if (node >= N_NODES) return;
  int lane = threadIdx.x & 63;
  int eo = lane >> 4, qfo = (lane & 15) << 2;

  float4 acc = gather_node_bf(h1, col, row_ptr[node], row_ptr[node + 1], eo, qfo,
                              make_float4(0.f, 0.f, 0.f, 0.f));
#pragma unroll
  for (int m = 16; m <= 32; m <<= 1) {           // reduce over eo
    acc.x += __shfl_xor(acc.x, m, 64);
    acc.y += __shfl_xor(acc.y, m, 64);
    acc.z += __shfl_xor(acc.z, m, 64);
    acc.w += __shfl_xor(acc.w, m, 64);
  }
  // every lane now holds agg1[node][qfo..qfo+3]; relu + dot + qfo-reduce
  float4 wv = *(const float4*)&w2fc[qfo];
  float p = fmaxf(acc.x, 0.f) * wv.x + fmaxf(acc.y, 0.f) * wv.y +
            fmaxf(acc.z, 0.f) * wv.z + fmaxf(acc.w, 0.f) * wv.w;
#pragma unroll
  for (int m = 1; m <= 8; m <<= 1) p += __shfl_xor(p, m, 64);
  if (lane == 0) z[node] = p;
}

// ---------------------------------------------------------------------------
// per-graph: sum z[col[i]] over all edges whose dst is in the graph's
// (sorted, contiguous) node segment; /node_count; sigmoid. z is 200KB ->
// L2-resident; this replaces the whole 102MB layer-2 gather.
__global__ __launch_bounds__(256) void graph_pool(const float* __restrict__ z,
                                                  const int* __restrict__ row_ptr,
                                                  const int* __restrict__ col,
                                                  const int* __restrict__ batch,
                                                  float* __restrict__ out) {
  __shared__ float sacc[4];
  int g = blockIdx.x;
  int tid = threadIdx.x, lane = tid & 63, w = tid >> 6;

  int lo = 0, hi = N_NODES;
  while (lo < hi) { int mid = (lo + hi) >> 1; if (batch[mid] < g) lo = mid + 1; else hi = mid; }
  const int start = lo;
  hi = N_NODES;
  while (lo < hi) { int mid = (lo + hi) >> 1; if (batch[mid] < g + 1) lo = mid + 1; else hi = mid; }
  const int end = lo;

  // edge range for the whole segment is contiguous in CSR
  const int e0 = row_ptr[start], e1 = row_ptr[end];
  float s = 0.f;
  for (int i = e0 + tid; i < e1; i += 256) s += z[col[i]];
#pragma unroll
  for (int off = 32; off; off >>= 1) s += __shfl_down(s, off, 64);
  if (lane == 0) sacc[w] = s;
  __syncthreads();
  if (tid == 0) {
    float v = sacc[0] + sacc[1] + sacc[2] + sacc[3];
    v /= fmaxf((float)(end - start), 1.f);
    out[g] = 1.f / (1.f + expf(-v));
  }
}

// ---------------------------------------------------------------------------
extern "C" void kernel_launch(void* const* d_in, const int* in_sizes, int n_in,
                              void* d_out, int out_size, void* d_ws, size_t ws_size,
                              hipStream_t stream) {
  const float* x     = (const float*)d_in[0];
  const int*   ei    = (const int*)d_in[1];   // [2, E]: src then dst
  const int*   batch = (const int*)d_in[2];
  const float* W1    = (const float*)d_in[3];
  const float* W2    = (const float*)d_in[4];
  const float* Wfc   = (const float*)d_in[5];
  float*       out   = (float*)d_out;

  const int* src = ei;
  const int* dst = ei + N_EDGES;

  // workspace layout (~14 MB, all disjoint)
  char* ws = (char*)d_ws;
  unsigned short* h1 = (unsigned short*)(ws);                  // [N,64] bf16
  float* z    = (float*)(ws + (size_t)N_NODES * DIM * 2);      // [N]
  float* w2fc = z + N_NODES;                                   // [64]
  int*   cnt  = (int*)(w2fc + 64);                             // [NCNT]
  int*   partials = cnt + NCNT;                                // [P2_NBLK]
  unsigned int* ebuf = (unsigned int*)(partials + P2_NBLK);    // [E]
  int*   col        = (int*)(ebuf + N_EDGES);                  // [E]
  int*   row_ptr    = col + N_EDGES;                           // [N+1]
  int*   bucket_ptr = row_ptr + N_NODES + 1;                   // [NBKT+1]

  // tiny precompute + CSR front half
  make_w2fc<<<1, 64, 0, stream>>>(W2, Wfc, w2fc);
  bhist<<<BH_BLK, 256, 0, stream>>>(dst, cnt);
  psum512<<<P2_NBLK, 512, 0, stream>>>(cnt, partials);
  scan_partials<<<1, 256, 0, stream>>>(partials);
  sblocks512<<<P2_NBLK, 512, 0, stream>>>(cnt, partials, bucket_ptr);

  // gemm1 (h1 = bf16(x@W1)) || bucket-sorted edge scatter
  gemm1_bscatter<<<GGRID + BH_BLK, 256, 0, stream>>>(x, W1, h1, src, dst, cnt, ebuf);
  bucket_to_csr<<<NBKT, 256, 0, stream>>>(ebuf, bucket_ptr, row_ptr, col);

  // layer-1 gather + relu + (W2@Wfc) dot -> z[N]
  gather_z<<<(N_NODES + 3) / 4, 256, 0, stream>>>(h1, row_ptr, col, w2fc, z);

  // per-graph edge-sum of z, mean, sigmoid
  graph_pool<<<N_GRAPHS, 256, 0, stream>>>(z, row_ptr, col, batch, out);
}

// Round 11
// 151.379 us; speedup vs baseline: 5.4666x; 1.0587x over previous
//
#include <hip/hip_runtime.h>
#include <cmath>

#define N_NODES 50000
#define N_EDGES 800000
#define N_FEAT 128
#define DIM 64
#define N_GRAPHS 512
#define GGRID ((N_NODES + 63) / 64)         // 782 gemm1 tiles / buckets
#define NBKT GGRID                          // bucket = dst>>6
#define BH_BLK 128                          // bucket-sort blocks
#define EPB (N_EDGES / BH_BLK)              // 6250 edges per sort block
#define NCNT (NBKT * BH_BLK)                // 100096 count-matrix entries
#define P2_NBLK ((NCNT + 511) / 512)        // 196 scan blocks
#define BKT_CAP 2048                        // max bucket edges (mean 1024, +32 sigma)

// bf16 storage helpers (RNE). Storage-only: all math in fp32.
__device__ __forceinline__ unsigned short f2bf(float f) {
  union { float f; unsigned int u; } v; v.f = f;
  return (unsigned short)((v.u + 0x7FFFu + ((v.u >> 16) & 1u)) >> 16);
}
__device__ __forceinline__ float bf2f(unsigned short u) {
  union { unsigned int u; float f; } v; v.u = (unsigned int)u << 16;
  return v.f;
}

// ---------------------------------------------------------------------------
// blocks [0,BH_BLK): per-block bucket histogram of dst>>6 (cnt bucket-major).
// block BH_BLK: w2fc = W2 @ Wfc (collapses gemm2+FC into one 64-vector).
__global__ __launch_bounds__(256) void bhist_w2fc(const int* __restrict__ dst,
                                                  int* __restrict__ cnt,
                                                  const float* __restrict__ W2,
                                                  const float* __restrict__ Wfc,
                                                  float* __restrict__ w2fc) {
  if (blockIdx.x == BH_BLK) {
    int k = threadIdx.x;
    if (k < 64) {
      float s = 0.f;
#pragma unroll 8
      for (int j = 0; j < 64; j++) s += W2[k * 64 + j] * Wfc[j];
      w2fc[k] = s;
    }
    return;
  }
  __shared__ int lh[NBKT];
  const int tid = threadIdx.x, k = blockIdx.x;
  for (int i = tid; i < NBKT; i += 256) lh[i] = 0;
  __syncthreads();
  const int base = k * EPB;
  for (int j = tid; j < EPB; j += 256)
    atomicAdd(&lh[dst[base + j] >> 6], 1);
  __syncthreads();
  for (int i = tid; i < NBKT; i += 256) cnt[i * BH_BLK + k] = lh[i];
}

// ---------------------------------------------------------------------------
// hierarchical exclusive scan over cnt[NCNT] (in-place) + bucket_ptr extract
__global__ __launch_bounds__(512) void psum512(const int* __restrict__ cnt,
                                               int* __restrict__ partials) {
  __shared__ int ws[8];
  int gid = blockIdx.x * 512 + threadIdx.x;
  int v = (gid < NCNT) ? cnt[gid] : 0;
#pragma unroll
  for (int off = 32; off; off >>= 1) v += __shfl_down(v, off, 64);
  int lane = threadIdx.x & 63, w = threadIdx.x >> 6;
  if (lane == 0) ws[w] = v;
  __syncthreads();
  if (threadIdx.x == 0) {
    int s = 0;
#pragma unroll
    for (int i = 0; i < 8; i++) s += ws[i];
    partials[blockIdx.x] = s;
  }
}

__global__ __launch_bounds__(256) void scan_partials(int* __restrict__ partials) {
  __shared__ int buf[256];
  int tid = threadIdx.x;
  int v = (tid < P2_NBLK) ? partials[tid] : 0;
  buf[tid] = v;
  __syncthreads();
  for (int off = 1; off < 256; off <<= 1) {
    int t = (tid >= off) ? buf[tid - off] : 0;
    __syncthreads();
    buf[tid] += t;
    __syncthreads();
  }
  if (tid < P2_NBLK) partials[tid] = buf[tid] - v;   // exclusive
}

__global__ __launch_bounds__(512) void sblocks512(int* __restrict__ cnt,
                                                  const int* __restrict__ partials,
                                                  int* __restrict__ bucket_ptr) {
  __shared__ int buf[512];
  int tid = threadIdx.x;
  int gid = blockIdx.x * 512 + tid;
  int v = (gid < NCNT) ? cnt[gid] : 0;
  buf[tid] = v;
  __syncthreads();
  for (int off = 1; off < 512; off <<= 1) {
    int t = (tid >= off) ? buf[tid - off] : 0;
    __syncthreads();
    buf[tid] += t;
    __syncthreads();
  }
  int excl = buf[tid] - v + partials[blockIdx.x];
  if (gid < NCNT) {
    cnt[gid] = excl;                                  // in-place offsets
    if ((gid & (BH_BLK - 1)) == 0) bucket_ptr[gid / BH_BLK] = excl;
    if (gid == NCNT - 1) bucket_ptr[NBKT] = excl + v; // == N_EDGES
  }
}

// ---------------------------------------------------------------------------
// GEMM body for gemm1: out[M][64] = A[M][128] @ W[128][64], bf16 output rows.
template<int K>
__device__ __forceinline__ void gemm_body_bf(const float* __restrict__ A,
                                             const float* __restrict__ W,
                                             unsigned short* __restrict__ out,
                                             int M, int row0, int tid,
                                             float* sX, float* sW) {
  const int tx = tid & 15, ty = tid >> 4;
  const int q = tid & 7, r0 = tid >> 3;
  float acc[4][4] = {};

  for (int kb = 0; kb < K; kb += 32) {
    __syncthreads();
    if ((kb & 63) == 0) {
#pragma unroll
      for (int i = 0; i < 16; i++)
        sW[i * 256 + tid] = W[kb * 64 + i * 256 + tid];
    }
#pragma unroll
    for (int rr = 0; rr < 64; rr += 32) {
      int r = r0 + rr;
      int gr = row0 + r;
      float4 v = make_float4(0.f, 0.f, 0.f, 0.f);
      if (gr < M) v = *(const float4*)&A[(size_t)gr * K + kb + q * 4];
      *(float4*)&sX[r * 36 + q * 4] = v;
    }
    __syncthreads();

    const int kw = kb & 63;
#pragma unroll 4
    for (int k = 0; k < 32; k += 4) {
      float4 wv[4];
#pragma unroll
      for (int kk = 0; kk < 4; kk++)
        wv[kk] = *(const float4*)&sW[(kw + k + kk) * 64 + tx * 4];
#pragma unroll
      for (int r = 0; r < 4; r++) {
        float4 xv = *(const float4*)&sX[(ty * 4 + r) * 36 + k];
        const float xs[4] = {xv.x, xv.y, xv.z, xv.w};
#pragma unroll
        for (int kk = 0; kk < 4; kk++) {
          acc[r][0] += xs[kk] * wv[kk].x;
          acc[r][1] += xs[kk] * wv[kk].y;
          acc[r][2] += xs[kk] * wv[kk].z;
          acc[r][3] += xs[kk] * wv[kk].w;
        }
      }
    }
  }

#pragma unroll
  for (int r = 0; r < 4; r++) {
    int gr = row0 + ty * 4 + r;
    if (gr < M) {
      ushort4 u;
      u.x = f2bf(acc[r][0]); u.y = f2bf(acc[r][1]);
      u.z = f2bf(acc[r][2]); u.w = f2bf(acc[r][3]);
      *(ushort4*)&out[(size_t)gr * 64 + tx * 4] = u;
    }
  }
}

// fused: blocks [0,GGRID) = gemm1 (x@W1 -> h1 bf16); blocks [GGRID..) run
// the bucket scatter (cnt offsets ready; gemm1 hides the scatter cost).
__global__ __launch_bounds__(256) void gemm1_bscatter(
    const float* __restrict__ x, const float* __restrict__ W1,
    unsigned short* __restrict__ h1, const int* __restrict__ src,
    const int* __restrict__ dst, const int* __restrict__ cnt,
    unsigned int* __restrict__ ebuf) {
  __shared__ float sX[64 * 36];
  __shared__ float sW[64 * 64];
  const int tid = threadIdx.x;
  if (blockIdx.x < GGRID) {
    gemm_body_bf<N_FEAT>(x, W1, h1, N_NODES, blockIdx.x * 64, tid, sX, sW);
  } else {
    int* loff = (int*)sX;                     // 782 ints fit easily
    const int k = blockIdx.x - GGRID;
    for (int i = tid; i < NBKT; i += 256) loff[i] = cnt[i * BH_BLK + k];
    __syncthreads();
    const int base = k * EPB;
    for (int j = tid; j < EPB; j += 256) {
      int e = base + j;
      int d = dst[e];
      int pos = atomicAdd(&loff[d >> 6], 1);
      ebuf[pos] = ((unsigned int)src[e] << 6) | (unsigned int)(d & 63);
    }
  }
}

// ---------------------------------------------------------------------------
// fused per-bucket CSR sort (in LDS) + layer-1 gather + relu + dot(w2fc) -> z.
// 782 blocks x 1024 threads (16 waves x 4 nodes = 64 nodes/block; 12512 waves
// total -- same gather parallelism as the node-parallel version).
__global__ __launch_bounds__(1024, 8) void gather_z_fused(
    const unsigned short* __restrict__ h1,
    const unsigned int* __restrict__ ebuf,
    const int* __restrict__ bucket_ptr,
    const float* __restrict__ w2fc,
    float* __restrict__ z) {
  __shared__ int colL[BKT_CAP];
  __shared__ int lstart[64];
  __shared__ int lcur[64];
  __shared__ float sw[64];
  const int tid = threadIdx.x;
  const int b = blockIdx.x;
  const int p0 = bucket_ptr[b];
  int cnt = bucket_ptr[b + 1] - p0;
  if (cnt > BKT_CAP) cnt = BKT_CAP;         // never triggers (max ~1150)

  if (tid < 64) { lstart[tid] = 0; sw[tid] = w2fc[tid]; }
  __syncthreads();
  // pass 1: 64-entry histogram of dst_local
  for (int i = tid; i < cnt; i += 1024)
    atomicAdd(&lstart[ebuf[p0 + i] & 63], 1);
  __syncthreads();
  // wave 0: exclusive scan over the 64 local degrees
  if (tid < 64) {
    int v = lstart[tid], s = v;
#pragma unroll
    for (int off = 1; off < 64; off <<= 1) {
      int t = __shfl_up(s, off, 64);
      if (tid >= off) s += t;
    }
    lstart[tid] = s - v;                    // stable start
    lcur[tid] = s - v;                      // fill cursor (-> end after pass 2)
  }
  __syncthreads();
  // pass 2: redistribute src ids into per-node segments of colL
  for (int i = tid; i < cnt; i += 1024) {
    unsigned int u = ebuf[p0 + i];
    int pos = atomicAdd(&lcur[u & 63], 1);
    colL[pos] = (int)(u >> 6);
  }
  __syncthreads();

  // gather: lane = (eo 0..3 edge slot, qfo feature-quad*4); 4 rows in flight
  const int lane = tid & 63, w = tid >> 6;
  const int eo = lane >> 4, qfo = (lane & 15) << 2;
#pragma unroll
  for (int ni = 0; ni < 4; ni++) {
    const int r = ni * 16 + w;
    const int i1 = lcur[r];
    int i = lstart[r];
    float4 acc = make_float4(0.f, 0.f, 0.f, 0.f);
    for (; i + 16 <= i1; i += 16) {
      int s0 = colL[i + eo];
      int s1 = colL[i + 4 + eo];
      int s2 = colL[i + 8 + eo];
      int s3 = colL[i + 12 + eo];
      ushort4 u0 = *(const ushort4*)&h1[(size_t)s0 * 64 + qfo];
      ushort4 u1 = *(const ushort4*)&h1[(size_t)s1 * 64 + qfo];
      ushort4 u2 = *(const ushort4*)&h1[(size_t)s2 * 64 + qfo];
      ushort4 u3 = *(const ushort4*)&h1[(size_t)s3 * 64 + qfo];
      acc.x += (bf2f(u0.x) + bf2f(u1.x)) + (bf2f(u2.x) + bf2f(u3.x));
      acc.y += (bf2f(u0.y) + bf2f(u1.y)) + (bf2f(u2.y) + bf2f(u3.y));
      acc.z += (bf2f(u0.z) + bf2f(u1.z)) + (bf2f(u2.z) + bf2f(u3.z));
      acc.w += (bf2f(u0.w) + bf2f(u1.w)) + (bf2f(u2.w) + bf2f(u3.w));
    }
    for (; i + 4 <= i1; i += 4) {
      int s = colL[i + eo];
      ushort4 u = *(const ushort4*)&h1[(size_t)s * 64 + qfo];
      acc.x += bf2f(u.x); acc.y += bf2f(u.y);
      acc.z += bf2f(u.z); acc.w += bf2f(u.w);
    }
    if (eo < i1 - i) {
      int s = colL[i + eo];
      ushort4 u = *(const ushort4*)&h1[(size_t)s * 64 + qfo];
      acc.x += bf2f(u.x); acc.y += bf2f(u.y);
      acc.z += bf2f(u.z); acc.w += bf2f(u.w);
    }
#pragma unroll
    for (int m = 16; m <= 32; m <<= 1) {          // reduce over eo
      acc.x += __shfl_xor(acc.x, m, 64);
      acc.y += __shfl_xor(acc.y, m, 64);
      acc.z += __shfl_xor(acc.z, m, 64);
      acc.w += __shfl_xor(acc.w, m, 64);
    }
    // relu + dot(w2fc) + reduce across the 16 feature-quads
    float p = fmaxf(acc.x, 0.f) * sw[qfo] + fmaxf(acc.y, 0.f) * sw[qfo + 1] +
              fmaxf(acc.z, 0.f) * sw[qfo + 2] + fmaxf(acc.w, 0.f) * sw[qfo + 3];
#pragma unroll
    for (int m = 1; m <= 8; m <<= 1) p += __shfl_xor(p, m, 64);
    int node = b * 64 + r;
    if (lane == 0 && node < N_NODES) z[node] = p;
  }
}

// ---------------------------------------------------------------------------
// per-graph: sum z[src] over edges whose dst lies in the graph's (sorted,
// contiguous) node range, walking ebuf bucket segments with a dst filter at
// graph-boundary buckets. z is 200KB -> L2-resident.
__global__ __launch_bounds__(256) void graph_pool(const float* __restrict__ z,
                                                  const unsigned int* __restrict__ ebuf,
                                                  const int* __restrict__ bucket_ptr,
                                                  const int* __restrict__ batch,
                                                  float* __restrict__ out) {
  __shared__ float sacc[4];
  int g = blockIdx.x;
  int tid = threadIdx.x, lane = tid & 63, w = tid >> 6;

  int lo = 0, hi = N_NODES;
  while (lo < hi) { int mid = (lo + hi) >> 1; if (batch[mid] < g) lo = mid + 1; else hi = mid; }
  const int start = lo;
  hi = N_NODES;
  while (lo < hi) { int mid = (lo + hi) >> 1; if (batch[mid] < g + 1) lo = mid + 1; else hi = mid; }
  const int end = lo;

  float s = 0.f;
  if (end > start) {
    const int b0 = start >> 6, b1 = ((end - 1) >> 6) + 1;
    for (int b = b0; b < b1; b++) {
      const int q0 = bucket_ptr[b], q1 = bucket_ptr[b + 1];
      const int base = b << 6;
      for (int i = q0 + tid; i < q1; i += 256) {
        unsigned int u = ebuf[i];
        int d = base + (int)(u & 63);
        if (d >= start && d < end) s += z[u >> 6];
      }
    }
  }
#pragma unroll
  for (int off = 32; off; off >>= 1) s += __shfl_down(s, off, 64);
  if (lane == 0) sacc[w] = s;
  __syncthreads();
  if (tid == 0) {
    float v = sacc[0] + sacc[1] + sacc[2] + sacc[3];
    v /= fmaxf((float)(end - start), 1.f);
    out[g] = 1.f / (1.f + expf(-v));
  }
}

// ---------------------------------------------------------------------------
extern "C" void kernel_launch(void* const* d_in, const int* in_sizes, int n_in,
                              void* d_out, int out_size, void* d_ws, size_t ws_size,
                              hipStream_t stream) {
  const float* x     = (const float*)d_in[0];
  const int*   ei    = (const int*)d_in[1];   // [2, E]: src then dst
  const int*   batch = (const int*)d_in[2];
  const float* W1    = (const float*)d_in[3];
  const float* W2    = (const float*)d_in[4];
  const float* Wfc   = (const float*)d_in[5];
  float*       out   = (float*)d_out;

  const int* src = ei;
  const int* dst = ei + N_EDGES;

  // workspace layout (~10.5 MB, all disjoint)
  char* ws = (char*)d_ws;
  unsigned short* h1 = (unsigned short*)(ws);                  // [N,64] bf16
  float* z    = (float*)(ws + (size_t)N_NODES * DIM * 2);      // [N]
  float* w2fc = z + N_NODES;                                   // [64]
  int*   cnt  = (int*)(w2fc + 64);                             // [NCNT]
  int*   partials = cnt + NCNT;                                // [P2_NBLK]
  unsigned int* ebuf = (unsigned int*)(partials + P2_NBLK);    // [E]
  int*   bucket_ptr  = (int*)(ebuf + N_EDGES);                 // [NBKT+1]

  // CSR front half: bucket histogram (+w2fc precompute) -> scan
  bhist_w2fc<<<BH_BLK + 1, 256, 0, stream>>>(dst, cnt, W2, Wfc, w2fc);
  psum512<<<P2_NBLK, 512, 0, stream>>>(cnt, partials);
  scan_partials<<<1, 256, 0, stream>>>(partials);
  sblocks512<<<P2_NBLK, 512, 0, stream>>>(cnt, partials, bucket_ptr);

  // gemm1 (h1 = bf16(x@W1)) || bucket-sorted edge scatter
  gemm1_bscatter<<<GGRID + BH_BLK, 256, 0, stream>>>(x, W1, h1, src, dst, cnt, ebuf);

  // fused per-bucket sort + layer-1 gather + relu + (W2@Wfc) dot -> z[N]
  gather_z_fused<<<NBKT, 1024, 0, stream>>>(h1, ebuf, bucket_ptr, w2fc, z);

  // per-graph edge-sum of z, mean, sigmoid
  graph_pool<<<N_GRAPHS, 256, 0, stream>>>(z, ebuf, bucket_ptr, batch, out);
}